// Round 8
// baseline (155.842 us; speedup 1.0000x reference)
//
#include <hip/hip_runtime.h>
#include <math.h>

#define N_POSE   1024
#define M_TRAIN  10000
#define NJOINT   21
#define KNEIGH   5
#define CLIPV    (1.0f - 1e-7f)
#define PI_F     3.14159265358979f
#define HPI_F    1.57079632679490f
#define BIGF     1e30f
#define QN_FLOATS (N_POSE * NJOINT * 4)  // normalized-pose staging in ws

// one-shot: normalize all query quats so the hot loop has no rsqrt
__global__ __launch_bounds__(256)
void pose_norm_kernel(const float* __restrict__ pose, float* __restrict__ qn) {
    int i = blockIdx.x * blockDim.x + threadIdx.x;
    if (i >= N_POSE * NJOINT) return;
    float4 v = ((const float4*)pose)[i];
    float inv = rsqrtf(v.x * v.x + v.y * v.y + v.z * v.z + v.w * v.w);
    v.x *= inv; v.y *= inv; v.z *= inv; v.w *= inv;
    ((float4*)qn)[i] = v;
}

// thread = query row; q[21] pinned live in VGPRs. Train loads are made
// formally lane-dependent (opaque zero) so they compile to per-lane
// global_load_dwordx4: identical addresses coalesce to a single L1 line
// (broadcast), and VMEM pipelines deeply on vmcnt — no SGPR-capacity wall,
// no lgkmcnt serialization (the R6 stall).
// acos via A&S poly + copysign fold: sum_j acos = 21*pi/2 - sum_j copysign.
__global__ __launch_bounds__(64)
void pose_dist_kernel(const float* __restrict__ qn,
                      const float* __restrict__ train,
                      float* __restrict__ topk,
                      int chunks, int mchunk) {
    const int nb = blockIdx.x / chunks;   // query group
    const int cb = blockIdx.x % chunks;   // m-chunk
    const int n  = nb * 64 + threadIdx.x;

    float4 q[NJOINT];
    const float4* __restrict__ qp = (const float4*)qn + (size_t)n * NJOINT;
#pragma unroll
    for (int j = 0; j < NJOINT; ++j) q[j] = qp[j];
#pragma unroll
    for (int j = 0; j < NJOINT; ++j)
        asm volatile("" : "+v"(q[j].x), "+v"(q[j].y), "+v"(q[j].z), "+v"(q[j].w));

    int lzero = 0;
    asm volatile("" : "+v"(lzero));       // opaque per-lane 0: forces VMEM path

    float t0 = BIGF, t1 = BIGF, t2 = BIGF, t3 = BIGF, t4 = BIGF;
    const float4* __restrict__ tq =
        (const float4*)train + (size_t)cb * mchunk * NJOINT + lzero;

#pragma unroll 1
    for (int mi = 0; mi < mchunk; ++mi) {
        const float4* __restrict__ tm = tq + (size_t)mi * NJOINT;
        float a0 = 0.f, a1 = 0.f;     // two chains of copysign terms
#pragma unroll
        for (int j = 0; j < NJOINT; ++j) {
            float4 p = q[j];
            float4 u = tm[j];                         // per-lane load, uniform addr
            float d = u.x * p.x + u.y * p.y + u.z * p.z + u.w * p.w;
            float a = fminf(fabsf(d), CLIPV);
            float pl = fmaf(a, -0.0187293f, 0.0742610f);
            pl = fmaf(a, pl, -0.2121144f);
            pl = fmaf(a, pl, 1.5707288f);
            float r  = __builtin_amdgcn_sqrtf(1.0f - a) * pl;
            float cs = __builtin_copysignf(HPI_F - r, d);
            if (j & 1) a1 += cs; else a0 += cs;
        }
        float v = (NJOINT * HPI_F - (a0 + a1)) * 0.5f;
        t4 = fminf(t4, fmaxf(t3, v));
        t3 = fminf(t3, fmaxf(t2, v));
        t2 = fminf(t2, fmaxf(t1, v));
        t1 = fminf(t1, fmaxf(t0, v));
        t0 = fminf(t0, v);
    }

    float* w = topk + ((size_t)n * chunks + cb) * KNEIGH;
    w[0] = t0; w[1] = t1; w[2] = t2; w[3] = t3; w[4] = t4;
}

// one wave per query row: merge chunks*5 candidates -> mean of top-5
__global__ __launch_bounds__(64)
void pose_reduce_kernel(const float* __restrict__ topk, float* __restrict__ out,
                        int chunks) {
    const int n = blockIdx.x;
    const int lane = threadIdx.x;
    const int total = chunks * KNEIGH;
    const float* __restrict__ w = topk + (size_t)n * total;

    float t0 = BIGF, t1 = BIGF, t2 = BIGF, t3 = BIGF, t4 = BIGF;
    for (int i = lane; i < total; i += 64) {
        float v = w[i];
        t4 = fminf(t4, fmaxf(t3, v));
        t3 = fminf(t3, fmaxf(t2, v));
        t2 = fminf(t2, fmaxf(t1, v));
        t1 = fminf(t1, fmaxf(t0, v));
        t0 = fminf(t0, v);
    }

    float sum = 0.f;
#pragma unroll
    for (int r = 0; r < KNEIGH; ++r) {
        float v = t0; int who = lane;
        for (int off = 32; off; off >>= 1) {
            float ov = __shfl_xor(v, off);
            int   ow = __shfl_xor(who, off);
            if (ov < v || (ov == v && ow < who)) { v = ov; who = ow; }
        }
        sum += v;
        if (lane == who) { t0 = t1; t1 = t2; t2 = t3; t3 = t4; t4 = BIGF; }
    }
    if (lane == 0) out[n] = sum * (1.0f / KNEIGH);
}

extern "C" void kernel_launch(void* const* d_in, const int* in_sizes, int n_in,
                              void* d_out, int out_size, void* d_ws, size_t ws_size,
                              hipStream_t stream) {
    const float* pose  = (const float*)d_in[0];
    const float* train = (const float*)d_in[1];
    float* out  = (float*)d_out;
    float* qn   = (float*)d_ws;                 // QN_FLOATS floats
    float* topk = (float*)d_ws + QN_FLOATS;

    // largest chunk tier whose topk fits ws (all tiers divide 10000).
    // chunks=500 -> 8000 waves ~= 7.8/SIMD occupancy for latency hiding.
    size_t base = (size_t)QN_FLOATS * sizeof(float);
    int chunks = 500;
    if (base + (size_t)N_POSE * chunks * KNEIGH * sizeof(float) > ws_size) chunks = 250;
    if (base + (size_t)N_POSE * chunks * KNEIGH * sizeof(float) > ws_size) chunks = 125;
    if (base + (size_t)N_POSE * chunks * KNEIGH * sizeof(float) > ws_size) chunks = 50;
    if (base + (size_t)N_POSE * chunks * KNEIGH * sizeof(float) > ws_size) chunks = 10;
    const int mchunk = M_TRAIN / chunks;

    pose_norm_kernel<<<dim3((N_POSE * NJOINT + 255) / 256), dim3(256), 0, stream>>>(pose, qn);

    dim3 grid1((N_POSE / 64) * chunks);
    pose_dist_kernel<<<grid1, dim3(64), 0, stream>>>(qn, train, topk, chunks, mchunk);

    pose_reduce_kernel<<<dim3(N_POSE), dim3(64), 0, stream>>>(topk, out, chunks);
}

// Round 9
// 154.953 us; speedup vs baseline: 1.0057x; 1.0057x over previous
//
#include <hip/hip_runtime.h>
#include <math.h>

#define N_POSE   1024
#define M_TRAIN  10000
#define NJOINT   21
#define KNEIGH   5
#define CLIPV    (1.0f - 1e-7f)
#define HPI_F    1.57079632679490f
#define BIGF     1e30f
#define JH       11       // joints per half-lane (h=1: 10 real + 1 dummy)
#define QN_FLOATS (N_POSE * NJOINT * 4)  // normalized-pose staging in ws

// one-shot: normalize all query quats so the hot loop has no rsqrt
__global__ __launch_bounds__(256)
void pose_norm_kernel(const float* __restrict__ pose, float* __restrict__ qn) {
    int i = blockIdx.x * blockDim.x + threadIdx.x;
    if (i >= N_POSE * NJOINT) return;
    float4 v = ((const float4*)pose)[i];
    float inv = rsqrtf(v.x * v.x + v.y * v.y + v.z * v.z + v.w * v.w);
    v.x *= inv; v.y *= inv; v.z *= inv; v.w *= inv;
    ((float4*)qn)[i] = v;
}

// Lane pair (r, r+32) shares one query row: half h owns 11 joints -> per-thread
// q state = 44 floats; total live ~59 VGPR, fits the compiler's 64-reg budget
// BY CONSTRUCTION (no spill, no remat re-reads — the L1-thrash that capped
// every prior round). Train loads are per-lane VMEM (half-wave-uniform addr,
// 2 lines/instr, vmcnt-pipelined). 8000 single-wave blocks ~= 7.8 waves/SIMD
// of TLP cover. acos via A&S poly + copysign fold.
__global__ __launch_bounds__(64)
void pose_dist_kernel(const float* __restrict__ qn,
                      const float* __restrict__ train,
                      float* __restrict__ topk,
                      int chunks, int mchunk) {
    const int nb   = blockIdx.x / chunks;   // row-group (0..31)
    const int cb   = blockIdx.x % chunks;   // m-chunk
    const int lane = threadIdx.x;
    const int h    = lane >> 5;
    const int n    = nb * 32 + (lane & 31);
    const int jbase = h * JH;               // 0 or 11

    float4 q[JH];
    const float4* __restrict__ qp = (const float4*)qn + (size_t)n * NJOINT + jbase;
#pragma unroll
    for (int jj = 0; jj < JH; ++jj) {
        int o = jj; if (jbase + jj > NJOINT - 1) o = jj - 1;   // h=1 dummy reads j20
        q[jj] = qp[o];
    }
#pragma unroll
    for (int jj = 0; jj < JH; ++jj)
        asm volatile("" : "+v"(q[jj].x), "+v"(q[jj].y), "+v"(q[jj].z), "+v"(q[jj].w));

    float t0 = BIGF, t1 = BIGF, t2 = BIGF, t3 = BIGF, t4 = BIGF;
    const float4* __restrict__ tq =
        (const float4*)train + (size_t)cb * mchunk * NJOINT + jbase;

#pragma unroll 1
    for (int mi = 0; mi < mchunk; ++mi) {
        const float4* __restrict__ tm = tq + (size_t)mi * NJOINT;
        float a0 = 0.f, a1 = 0.f;    // two chains of copysign terms
#pragma unroll
        for (int jj = 0; jj < JH; ++jj) {
            int o = jj; if (jbase + jj > NJOINT - 1) o = jj - 1;
            float4 p = q[jj];
            float4 u = tm[o];                       // per-lane VMEM, 2 lines/instr
            float d = u.x * p.x + u.y * p.y + u.z * p.z + u.w * p.w;
            float a = fminf(fabsf(d), CLIPV);
            float pl = fmaf(a, -0.0187293f, 0.0742610f);
            pl = fmaf(a, pl, -0.2121144f);
            pl = fmaf(a, pl, 1.5707288f);
            float r  = __builtin_amdgcn_sqrtf(1.0f - a) * pl;
            float cs = __builtin_copysignf(HPI_F - r, d);
            if (jj == JH - 1) cs = h ? 0.f : cs;    // mask dummy joint
            if (jj & 1) a1 += cs; else a0 += cs;
        }
        float acc = a0 + a1;
        float v = (NJOINT * HPI_F - (acc + __shfl_xor(acc, 32))) * 0.5f;
        t4 = fminf(t4, fmaxf(t3, v));
        t3 = fminf(t3, fmaxf(t2, v));
        t2 = fminf(t2, fmaxf(t1, v));
        t1 = fminf(t1, fmaxf(t0, v));
        t0 = fminf(t0, v);
    }

    if (lane < 32) {
        float* w = topk + ((size_t)n * chunks + cb) * KNEIGH;
        w[0] = t0; w[1] = t1; w[2] = t2; w[3] = t3; w[4] = t4;
    }
}

// one wave per query row: merge chunks*5 candidates -> mean of top-5
__global__ __launch_bounds__(64)
void pose_reduce_kernel(const float* __restrict__ topk, float* __restrict__ out,
                        int chunks) {
    const int n = blockIdx.x;
    const int lane = threadIdx.x;
    const int total = chunks * KNEIGH;
    const float* __restrict__ w = topk + (size_t)n * total;

    float t0 = BIGF, t1 = BIGF, t2 = BIGF, t3 = BIGF, t4 = BIGF;
    for (int i = lane; i < total; i += 64) {
        float v = w[i];
        t4 = fminf(t4, fmaxf(t3, v));
        t3 = fminf(t3, fmaxf(t2, v));
        t2 = fminf(t2, fmaxf(t1, v));
        t1 = fminf(t1, fmaxf(t0, v));
        t0 = fminf(t0, v);
    }

    float sum = 0.f;
#pragma unroll
    for (int r = 0; r < KNEIGH; ++r) {
        float v = t0; int who = lane;
        for (int off = 32; off; off >>= 1) {
            float ov = __shfl_xor(v, off);
            int   ow = __shfl_xor(who, off);
            if (ov < v || (ov == v && ow < who)) { v = ov; who = ow; }
        }
        sum += v;
        if (lane == who) { t0 = t1; t1 = t2; t2 = t3; t3 = t4; t4 = BIGF; }
    }
    if (lane == 0) out[n] = sum * (1.0f / KNEIGH);
}

extern "C" void kernel_launch(void* const* d_in, const int* in_sizes, int n_in,
                              void* d_out, int out_size, void* d_ws, size_t ws_size,
                              hipStream_t stream) {
    const float* pose  = (const float*)d_in[0];
    const float* train = (const float*)d_in[1];
    float* out  = (float*)d_out;
    float* qn   = (float*)d_ws;                 // QN_FLOATS floats
    float* topk = (float*)d_ws + QN_FLOATS;

    // chunks=250 proven to fit ws in R6; tiers all divide 10000
    size_t base = (size_t)QN_FLOATS * sizeof(float);
    int chunks = 250;
    if (base + (size_t)N_POSE * chunks * KNEIGH * sizeof(float) > ws_size) chunks = 125;
    if (base + (size_t)N_POSE * chunks * KNEIGH * sizeof(float) > ws_size) chunks = 50;
    if (base + (size_t)N_POSE * chunks * KNEIGH * sizeof(float) > ws_size) chunks = 10;
    const int mchunk = M_TRAIN / chunks;

    pose_norm_kernel<<<dim3((N_POSE * NJOINT + 255) / 256), dim3(256), 0, stream>>>(pose, qn);

    dim3 grid1((N_POSE / 32) * chunks);   // 8000 single-wave blocks
    pose_dist_kernel<<<grid1, dim3(64), 0, stream>>>(qn, train, topk, chunks, mchunk);

    pose_reduce_kernel<<<dim3(N_POSE), dim3(64), 0, stream>>>(topk, out, chunks);
}

// Round 10
// 145.615 us; speedup vs baseline: 1.0702x; 1.0641x over previous
//
#include <hip/hip_runtime.h>
#include <math.h>

#define N_POSE   1024
#define M_TRAIN  10000
#define NJOINT   21
#define KNEIGH   5
#define CLIPV    (1.0f - 1e-7f)
#define HPI_F    1.57079632679490f
#define BIGF     1e30f
#define TPB      256
#define QN_FLOATS (N_POSE * NJOINT * 4)  // normalized-pose staging in ws

typedef float v4f __attribute__((ext_vector_type(4)));

// opaque load: result cannot be rematerialized by the register allocator
__device__ __forceinline__ v4f qload(const float* a) {
    v4f r;
    asm volatile("global_load_dwordx4 %0, %1, off" : "=v"(r) : "v"(a) : "memory");
    return r;
}

// one-shot: normalize all query quats so the hot loop has no rsqrt
__global__ __launch_bounds__(256)
void pose_norm_kernel(const float* __restrict__ pose, float* __restrict__ qn) {
    int i = blockIdx.x * blockDim.x + threadIdx.x;
    if (i >= N_POSE * NJOINT) return;
    float4 v = ((const float4*)pose)[i];
    float inv = rsqrtf(v.x * v.x + v.y * v.y + v.z * v.z + v.w * v.w);
    v.x *= inv; v.y *= inv; v.z *= inv; v.w *= inv;
    ((float4*)qn)[i] = v;
}

// 4 lanes (r, r+16, r+32, r+48) share one query row; role h owns 6 joint
// slots (h=0: j0-5; h>0: 5 real + 1 masked dummy). Per-thread q = 24 floats,
// loaded via opaque asm so it CANNOT be remat'd — the L1-thrash that capped
// every prior round. Train reads are 16-lane-uniform VMEM. Quad-sum via two
// shfl_xor. Top-5 kept on raw S (5 LARGEST, since dist = (21*pi/2 - S)/2 is
// decreasing in S) behind a mostly-skipped insert guard.
__global__ __launch_bounds__(TPB)
void pose_dist_kernel(const float* __restrict__ qn,
                      const float* __restrict__ train,
                      float* __restrict__ topk,
                      int chunks, int mchunk) {
    const int nb  = blockIdx.x / chunks;
    const int cb  = blockIdx.x % chunks;
    const int tid = threadIdx.x;
    const int wl  = tid & 63;             // lane in wave
    const int h   = wl >> 4;              // quad role 0..3
    const int n   = nb * 64 + (tid >> 6) * 16 + (wl & 15);
    const int jbase = (h == 0) ? 0 : (5 * h + 1);   // 0,6,11,16
    const int cnt   = (h == 0) ? 6 : 5;
    const int off5  = (cnt - 1) * 4;      // float offset of slot-5's joint
    const float mask5 = (h == 0) ? 1.0f : 0.0f;

    v4f q[6];
    const float* qb = qn + (size_t)n * (NJOINT * 4) + jbase * 4;
#pragma unroll
    for (int jj = 0; jj < 5; ++jj) q[jj] = qload(qb + jj * 4);
    q[5] = qload(qb + off5);
    asm volatile("s_waitcnt vmcnt(0)" ::: "memory");

    float t0 = -BIGF, t1 = -BIGF, t2 = -BIGF, t3 = -BIGF, t4 = -BIGF; // 5 largest S
    const float* tb = train + (size_t)cb * mchunk * (NJOINT * 4) + jbase * 4;

#pragma unroll 1
    for (int mi = 0; mi < mchunk; ++mi) {
        const float* tm = tb + (size_t)mi * (NJOINT * 4);
        float a0 = 0.f, a1 = 0.f;
#pragma unroll
        for (int jj = 0; jj < 6; ++jj) {
            float4 u = (jj < 5) ? ((const float4*)tm)[jj]
                                : *(const float4*)(tm + off5);
            v4f p = q[jj];
            float d = u.x * p.x + u.y * p.y + u.z * p.z + u.w * p.w;
            float a = fminf(fabsf(d), CLIPV);
            float pl = fmaf(a, -0.0187293f, 0.0742610f);
            pl = fmaf(a, pl, -0.2121144f);
            pl = fmaf(a, pl, 1.5707288f);
            float r  = __builtin_amdgcn_sqrtf(1.0f - a) * pl;
            float cs = __builtin_copysignf(HPI_F - r, d);
            if (jj == 5) cs *= mask5;               // kill dummy slot (h>0)
            if (jj & 1) a1 += cs; else a0 += cs;
        }
        float S = a0 + a1;
        S += __shfl_xor(S, 16);
        S += __shfl_xor(S, 32);                     // full quad sum, all lanes
        if (S > t4) {                               // rarely taken in steady state
            t4 = fmaxf(t4, fminf(t3, S));
            t3 = fmaxf(t3, fminf(t2, S));
            t2 = fmaxf(t2, fminf(t1, S));
            t1 = fmaxf(t1, fminf(t0, S));
            t0 = fmaxf(t0, S);
        }
    }

    if (wl < 16) {                                  // one writer per row
        float* w = topk + ((size_t)n * chunks + cb) * KNEIGH;
        w[0] = t0; w[1] = t1; w[2] = t2; w[3] = t3; w[4] = t4;
    }
}

// one wave per query row: transform S -> dist, merge chunks*5 -> mean of top-5
__global__ __launch_bounds__(64)
void pose_reduce_kernel(const float* __restrict__ topk, float* __restrict__ out,
                        int chunks) {
    const int n = blockIdx.x;
    const int lane = threadIdx.x;
    const int total = chunks * KNEIGH;
    const float* __restrict__ w = topk + (size_t)n * total;

    float t0 = BIGF, t1 = BIGF, t2 = BIGF, t3 = BIGF, t4 = BIGF;
    for (int i = lane; i < total; i += 64) {
        float v = (NJOINT * HPI_F - w[i]) * 0.5f;   // S -> distance
        t4 = fminf(t4, fmaxf(t3, v));
        t3 = fminf(t3, fmaxf(t2, v));
        t2 = fminf(t2, fmaxf(t1, v));
        t1 = fminf(t1, fmaxf(t0, v));
        t0 = fminf(t0, v);
    }

    float sum = 0.f;
#pragma unroll
    for (int r = 0; r < KNEIGH; ++r) {
        float v = t0; int who = lane;
        for (int off = 32; off; off >>= 1) {
            float ov = __shfl_xor(v, off);
            int   ow = __shfl_xor(who, off);
            if (ov < v || (ov == v && ow < who)) { v = ov; who = ow; }
        }
        sum += v;
        if (lane == who) { t0 = t1; t1 = t2; t2 = t3; t3 = t4; t4 = BIGF; }
    }
    if (lane == 0) out[n] = sum * (1.0f / KNEIGH);
}

extern "C" void kernel_launch(void* const* d_in, const int* in_sizes, int n_in,
                              void* d_out, int out_size, void* d_ws, size_t ws_size,
                              hipStream_t stream) {
    const float* pose  = (const float*)d_in[0];
    const float* train = (const float*)d_in[1];
    float* out  = (float*)d_out;
    float* qn   = (float*)d_ws;                 // QN_FLOATS floats
    float* topk = (float*)d_ws + QN_FLOATS;

    size_t base = (size_t)QN_FLOATS * sizeof(float);
    int chunks = 250;
    if (base + (size_t)N_POSE * chunks * KNEIGH * sizeof(float) > ws_size) chunks = 125;
    if (base + (size_t)N_POSE * chunks * KNEIGH * sizeof(float) > ws_size) chunks = 50;
    if (base + (size_t)N_POSE * chunks * KNEIGH * sizeof(float) > ws_size) chunks = 10;
    const int mchunk = M_TRAIN / chunks;

    pose_norm_kernel<<<dim3((N_POSE * NJOINT + 255) / 256), dim3(256), 0, stream>>>(pose, qn);

    // 16 row-groups x chunks blocks of 256 threads (4 waves) -> 16000 waves:
    // enough blocks to saturate 32 waves/CU without hitting the WG/CU cap.
    dim3 grid1((N_POSE / 64) * chunks);
    pose_dist_kernel<<<grid1, dim3(TPB), 0, stream>>>(qn, train, topk, chunks, mchunk);

    pose_reduce_kernel<<<dim3(N_POSE), dim3(64), 0, stream>>>(topk, out, chunks);
}

// Round 11
// 111.625 us; speedup vs baseline: 1.3961x; 1.3045x over previous
//
#include <hip/hip_runtime.h>
#include <math.h>

#define N_POSE   1024
#define M_TRAIN  10000
#define NJOINT   21
#define KNEIGH   5
#define CLIPV    (1.0f - 1e-7f)
#define HPI_F    1.57079632679490f
#define BIGF     1e30f
#define TPB      256
#define QN_FLOATS (N_POSE * NJOINT * 4)  // normalized-pose staging in ws

// one-shot: normalize all query quats so the hot loop has no rsqrt
__global__ __launch_bounds__(256)
void pose_norm_kernel(const float* __restrict__ pose, float* __restrict__ qn) {
    int i = blockIdx.x * blockDim.x + threadIdx.x;
    if (i >= N_POSE * NJOINT) return;
    float4 v = ((const float4*)pose)[i];
    float inv = rsqrtf(v.x * v.x + v.y * v.y + v.z * v.z + v.w * v.w);
    v.x *= inv; v.y *= inv; v.z *= inv; v.w *= inv;
    ((float4*)qn)[i] = v;
}

// R6's hot loop verbatim (best measured op stream: 58us busy = 1.3x ideal),
// re-gridded for occupancy: 256-thread blocks (4 waves, thread = query row)
// x chunks=500 -> 8000 waves = ~31 waves/CU requested, so the per-m s_load
// lgkm waits are covered by ~8 co-resident waves/SIMD instead of 2.5 (R6's
// 40% stall). Train reads wave-uniform -> scalarized s_load. topk stored in
// [cb][n][k] layout so consecutive threads write adjacent 20B (coalesced,
// kills R7's 2x write amplification).
__global__ __launch_bounds__(TPB)
void pose_dist_kernel(const float* __restrict__ qn,
                      const float* __restrict__ train,
                      float* __restrict__ topk,
                      int chunks, int mchunk) {
    const int nb = blockIdx.x / chunks;   // row-group (0..3)
    const int cb = blockIdx.x % chunks;   // m-chunk
    const int n  = nb * TPB + threadIdx.x;

    float4 q[NJOINT];
    const float4* __restrict__ qp = (const float4*)qn + (size_t)n * NJOINT;
#pragma unroll
    for (int j = 0; j < NJOINT; ++j) q[j] = qp[j];
#pragma unroll
    for (int j = 0; j < NJOINT; ++j)
        asm volatile("" : "+v"(q[j].x), "+v"(q[j].y), "+v"(q[j].z), "+v"(q[j].w));

    float t0 = BIGF, t1 = BIGF, t2 = BIGF, t3 = BIGF, t4 = BIGF;
    const float4* __restrict__ tq = (const float4*)train + (size_t)cb * mchunk * NJOINT;

#pragma unroll 1
    for (int mi = 0; mi < mchunk; ++mi) {
        const float4* __restrict__ tm = tq + (size_t)mi * NJOINT;
        float a0 = 0.f, a1 = 0.f;     // two chains of copysign terms
#pragma unroll
        for (int j = 0; j < NJOINT; ++j) {
            float4 p = q[j];
            float4 u = tm[j];                         // wave-uniform -> s_load
            float d = u.x * p.x + u.y * p.y + u.z * p.z + u.w * p.w;
            float a = fminf(fabsf(d), CLIPV);
            float pl = fmaf(a, -0.0187293f, 0.0742610f);
            pl = fmaf(a, pl, -0.2121144f);
            pl = fmaf(a, pl, 1.5707288f);
            float r  = __builtin_amdgcn_sqrtf(1.0f - a) * pl;
            float cs = __builtin_copysignf(HPI_F - r, d);
            if (j & 1) a1 += cs; else a0 += cs;
        }
        float v = (NJOINT * HPI_F - (a0 + a1)) * 0.5f;
        t4 = fminf(t4, fmaxf(t3, v));
        t3 = fminf(t3, fmaxf(t2, v));
        t2 = fminf(t2, fmaxf(t1, v));
        t1 = fminf(t1, fmaxf(t0, v));
        t0 = fminf(t0, v);
    }

    // [cb][n][k] layout: adjacent rows -> adjacent 20B -> coalesced stores
    float* w = topk + ((size_t)cb * N_POSE + n) * KNEIGH;
    w[0] = t0; w[1] = t1; w[2] = t2; w[3] = t3; w[4] = t4;
}

// one wave per query row: merge chunks*5 candidates -> mean of top-5
__global__ __launch_bounds__(64)
void pose_reduce_kernel(const float* __restrict__ topk, float* __restrict__ out,
                        int chunks) {
    const int n = blockIdx.x;
    const int lane = threadIdx.x;
    const int total = chunks * KNEIGH;

    float t0 = BIGF, t1 = BIGF, t2 = BIGF, t3 = BIGF, t4 = BIGF;
    for (int i = lane; i < total; i += 64) {
        int cb = i / KNEIGH, k = i % KNEIGH;
        float v = topk[((size_t)cb * N_POSE + n) * KNEIGH + k];
        t4 = fminf(t4, fmaxf(t3, v));
        t3 = fminf(t3, fmaxf(t2, v));
        t2 = fminf(t2, fmaxf(t1, v));
        t1 = fminf(t1, fmaxf(t0, v));
        t0 = fminf(t0, v);
    }

    float sum = 0.f;
#pragma unroll
    for (int r = 0; r < KNEIGH; ++r) {
        float v = t0; int who = lane;
        for (int off = 32; off; off >>= 1) {
            float ov = __shfl_xor(v, off);
            int   ow = __shfl_xor(who, off);
            if (ov < v || (ov == v && ow < who)) { v = ov; who = ow; }
        }
        sum += v;
        if (lane == who) { t0 = t1; t1 = t2; t2 = t3; t3 = t4; t4 = BIGF; }
    }
    if (lane == 0) out[n] = sum * (1.0f / KNEIGH);
}

extern "C" void kernel_launch(void* const* d_in, const int* in_sizes, int n_in,
                              void* d_out, int out_size, void* d_ws, size_t ws_size,
                              hipStream_t stream) {
    const float* pose  = (const float*)d_in[0];
    const float* train = (const float*)d_in[1];
    float* out  = (float*)d_out;
    float* qn   = (float*)d_ws;                 // QN_FLOATS floats
    float* topk = (float*)d_ws + QN_FLOATS;

    // chunks=500 -> 8000 waves (~31/CU requested). Tiers all divide 10000.
    size_t base = (size_t)QN_FLOATS * sizeof(float);
    int chunks = 500;
    if (base + (size_t)N_POSE * chunks * KNEIGH * sizeof(float) > ws_size) chunks = 250;
    if (base + (size_t)N_POSE * chunks * KNEIGH * sizeof(float) > ws_size) chunks = 125;
    if (base + (size_t)N_POSE * chunks * KNEIGH * sizeof(float) > ws_size) chunks = 50;
    if (base + (size_t)N_POSE * chunks * KNEIGH * sizeof(float) > ws_size) chunks = 10;
    const int mchunk = M_TRAIN / chunks;

    pose_norm_kernel<<<dim3((N_POSE * NJOINT + 255) / 256), dim3(256), 0, stream>>>(pose, qn);

    dim3 grid1((N_POSE / TPB) * chunks);   // 4 row-groups x 500 chunks = 2000 blocks
    pose_dist_kernel<<<grid1, dim3(TPB), 0, stream>>>(qn, train, topk, chunks, mchunk);

    pose_reduce_kernel<<<dim3(N_POSE), dim3(64), 0, stream>>>(topk, out, chunks);
}